// Round 1
// baseline (639.536 us; speedup 1.0000x reference)
//
#include <hip/hip_runtime.h>

#define NN 268
#define NE 8192

// ---------------------------------------------------------------------------
// K1: per-graph edge prep. deg by src, dinv, nw = -dinv[src]*w*dinv[dst]
// (self-loops zeroed), CSR sorted by dst -> (src, nw) pairs + row_ptr.
// ---------------------------------------------------------------------------
__global__ __launch_bounds__(256) void k_edge_prep(
    const int* __restrict__ ei1, const float* __restrict__ ea1,
    const int* __restrict__ ei2, const float* __restrict__ ea2,
    int2* __restrict__ csr, int* __restrict__ rowptr) {
  int g = blockIdx.x;
  const int* ei = (g < 64) ? (ei1 + (size_t)g * 2 * NE) : (ei2 + (size_t)(g - 64) * 2 * NE);
  const float* ea = (g < 64) ? (ea1 + (size_t)g * NE) : (ea2 + (size_t)(g - 64) * NE);
  __shared__ float deg[NN];
  __shared__ float dinv[NN];
  __shared__ int cnt[NN];
  __shared__ int rp[NN + 1];
  int t = threadIdx.x;
  for (int n = t; n < NN; n += 256) { deg[n] = 0.f; cnt[n] = 0; }
  __syncthreads();
  for (int e = t; e < NE; e += 256) {
    int s = ei[e], d = ei[NE + e];
    float w = ea[e];
    if (s == d) w = 0.f;
    atomicAdd(&deg[s], w);
    atomicAdd(&cnt[d], 1);
  }
  __syncthreads();
  for (int n = t; n < NN; n += 256) {
    float dv = deg[n];
    dinv[n] = dv > 0.f ? rsqrtf(dv) : 0.f;
  }
  __syncthreads();
  if (t == 0) {
    int acc = 0;
    for (int n = 0; n < NN; ++n) { rp[n] = acc; acc += cnt[n]; }
    rp[NN] = acc;
  }
  __syncthreads();
  for (int n = t; n <= NN; n += 256) rowptr[g * 272 + n] = rp[n];
  for (int n = t; n < NN; n += 256) cnt[n] = rp[n];
  __syncthreads();
  for (int e = t; e < NE; e += 256) {
    int s = ei[e], d = ei[NE + e];
    float w = ea[e];
    if (s == d) w = 0.f;
    float nw = -dinv[s] * w * dinv[d];
    int pos = atomicAdd(&cnt[d], 1);
    csr[(size_t)g * NE + pos] = make_int2(s, __float_as_int(nw));
  }
}

// ---------------------------------------------------------------------------
// K2/K4: batched GEMM  Y[g] = A[g] @ [W[0]|W[1]|W[2]]  (per-graph A, shared W)
// A[g]: [268 x KD] row-major. W: [3][KD][SN]. Y: [g][268][NC], NC = 3*SN.
// Tile: 64 rows x NC cols per block, 256 threads, 4 x TNT micro-tile.
// ---------------------------------------------------------------------------
template <int KD, int NC, int SN, int TNT>
__global__ __launch_bounds__(256) void k_gemm_cat(
    const float* __restrict__ A1, const float* __restrict__ A2,
    const float* __restrict__ W, float* __restrict__ Y) {
  int g = blockIdx.y;
  int m0 = blockIdx.x * 64;
  const float* A = (g < 64) ? (A1 + (size_t)g * NN * KD) : (A2 + (size_t)(g - 64) * NN * KD);
  float* Yg = Y + (size_t)g * NN * NC;
  __shared__ float As[64][17];
  __shared__ float Bs[16][NC];
  int t = threadIdx.x;
  int tx = t & 15, ty = t >> 4;
  float acc[4][TNT];
#pragma unroll
  for (int i = 0; i < 4; ++i)
#pragma unroll
    for (int j = 0; j < TNT; ++j) acc[i][j] = 0.f;

  for (int k0 = 0; k0 < KD; k0 += 16) {
    int klim = KD - k0; if (klim > 16) klim = 16;
    {
      int kk = t & 15, rb = t >> 4;
#pragma unroll
      for (int i = 0; i < 4; ++i) {
        int r = rb + i * 16;
        int row = m0 + r;
        As[r][kk] = (row < NN && kk < klim) ? A[(size_t)row * KD + k0 + kk] : 0.f;
      }
    }
    for (int i = t; i < 16 * NC; i += 256) {
      int kk = i / NC, c = i - kk * NC;
      int kb = c / SN, j = c - kb * SN;
      Bs[kk][c] = (kk < klim) ? W[((size_t)kb * KD + (k0 + kk)) * SN + j] : 0.f;
    }
    __syncthreads();
#pragma unroll
    for (int kk = 0; kk < 16; ++kk) {
      float a[4];
#pragma unroll
      for (int i = 0; i < 4; ++i) a[i] = As[ty * 4 + i][kk];
#pragma unroll
      for (int j = 0; j < TNT; ++j) {
        float b = Bs[kk][tx * TNT + j];
#pragma unroll
        for (int i = 0; i < 4; ++i) acc[i][j] += a[i] * b;
      }
    }
    __syncthreads();
  }
#pragma unroll
  for (int i = 0; i < 4; ++i) {
    int row = m0 + ty * 4 + i;
    if (row < NN) {
#pragma unroll
      for (int j = 0; j < TNT; ++j) Yg[(size_t)row * NC + tx * TNT + j] = acc[i][j];
    }
  }
}

// ---------------------------------------------------------------------------
// CSR gather: dst[n][0:16] = sum_{e: dst_e = n} nw_e * src_lds[src_e][0:16]
// items = (node, 4-float group). No atomics (one writer per output).
// ---------------------------------------------------------------------------
__device__ __forceinline__ void gather16(float* __restrict__ dst, const float* __restrict__ src,
                                         const int2* __restrict__ cs, const int* __restrict__ rp,
                                         int t) {
  for (int item = t; item < NN * 4; item += 256) {
    int n = item >> 2, fg = item & 3;
    float4 r = make_float4(0.f, 0.f, 0.f, 0.f);
    int e1 = rp[n + 1];
    for (int e = rp[n]; e < e1; ++e) {
      int2 p = cs[e];
      float nw = __int_as_float(p.y);
      float4 sv = *(const float4*)(src + p.x * 16 + fg * 4);
      r.x += nw * sv.x; r.y += nw * sv.y; r.z += nw * sv.z; r.w += nw * sv.w;
    }
    *(float4*)(dst + n * 16 + fg * 4) = r;
  }
}

// ---------------------------------------------------------------------------
// K3: cheb1 combine. H1 = relu(Y0 - Y2 + L*Y1 + 2*L*(L*Y2) + b1)
// Y cols: [0:64)=Y0, [64:128)=Y1, [128:192)=Y2. One block per (graph, 16-feat chunk).
// ---------------------------------------------------------------------------
__global__ __launch_bounds__(256) void k_cheb1(
    const float* __restrict__ Y, const int2* __restrict__ csr, const int* __restrict__ rowptr,
    const float* __restrict__ b1, float* __restrict__ H1) {
  int g = blockIdx.y, fb = blockIdx.x * 16;
  const float* Yg = Y + (size_t)g * NN * 192;
  const int2* cs = csr + (size_t)g * NE;
  __shared__ __align__(16) float S[NN * 16];
  __shared__ __align__(16) float T[NN * 16];
  __shared__ int rp[NN + 1];
  int t = threadIdx.x;
  for (int i = t; i < NN + 1; i += 256) rp[i] = rowptr[g * 272 + i];
  for (int i = t; i < NN * 16; i += 256) {
    int n = i >> 4, f = i & 15;
    S[i] = Yg[n * 192 + 128 + fb + f];  // Y2 chunk
  }
  __syncthreads();
  gather16(T, S, cs, rp, t);  // T = L*Y2
  __syncthreads();
  gather16(S, T, cs, rp, t);  // S = L*L*Y2
  __syncthreads();
  for (int i = t; i < NN * 16; i += 256) {
    int n = i >> 4, f = i & 15;
    T[i] = Yg[n * 192 + 64 + fb + f];  // Y1 chunk
  }
  __syncthreads();
  for (int item = t; item < NN * 4; item += 256) {
    int n = item >> 2, fg = item & 3;
    float4 r = make_float4(0.f, 0.f, 0.f, 0.f);
    int e1 = rp[n + 1];
    for (int e = rp[n]; e < e1; ++e) {
      int2 p = cs[e];
      float nw = __int_as_float(p.y);
      float4 sv = *(const float4*)(T + p.x * 16 + fg * 4);  // L*Y1
      r.x += nw * sv.x; r.y += nw * sv.y; r.z += nw * sv.z; r.w += nw * sv.w;
    }
    int f0 = fb + fg * 4;
    float4 y0 = *(const float4*)(Yg + n * 192 + f0);
    float4 y2 = *(const float4*)(Yg + n * 192 + 128 + f0);
    float4 s2 = *(const float4*)(S + n * 16 + fg * 4);
    float4 bb = *(const float4*)(b1 + f0);
    float4 v;
    v.x = fmaxf(y0.x - y2.x + r.x + 2.f * s2.x + bb.x, 0.f);
    v.y = fmaxf(y0.y - y2.y + r.y + 2.f * s2.y + bb.y, 0.f);
    v.z = fmaxf(y0.z - y2.z + r.z + 2.f * s2.z + bb.z, 0.f);
    v.w = fmaxf(y0.w - y2.w + r.w + 2.f * s2.w + bb.w, 0.f);
    *(float4*)(H1 + ((size_t)g * NN + n) * 64 + f0) = v;
  }
}

// ---------------------------------------------------------------------------
// K5: cheb2 combine. Same as K3 with F=32, Yb cols [0:32|32:64|64:96],
// output written TRANSPOSED: H2T[g][f][n]  (rows of classifier GEMM).
// ---------------------------------------------------------------------------
__global__ __launch_bounds__(256) void k_cheb2(
    const float* __restrict__ Yb, const int2* __restrict__ csr, const int* __restrict__ rowptr,
    const float* __restrict__ b4, float* __restrict__ H2T) {
  int g = blockIdx.y, fb = blockIdx.x * 16;
  const float* Yg = Yb + (size_t)g * NN * 96;
  const int2* cs = csr + (size_t)g * NE;
  __shared__ __align__(16) float S[NN * 16];
  __shared__ __align__(16) float T[NN * 16];
  __shared__ int rp[NN + 1];
  int t = threadIdx.x;
  for (int i = t; i < NN + 1; i += 256) rp[i] = rowptr[g * 272 + i];
  for (int i = t; i < NN * 16; i += 256) {
    int n = i >> 4, f = i & 15;
    S[i] = Yg[n * 96 + 64 + fb + f];  // Y2' chunk
  }
  __syncthreads();
  gather16(T, S, cs, rp, t);
  __syncthreads();
  gather16(S, T, cs, rp, t);
  __syncthreads();
  for (int i = t; i < NN * 16; i += 256) {
    int n = i >> 4, f = i & 15;
    T[i] = Yg[n * 96 + 32 + fb + f];  // Y1' chunk
  }
  __syncthreads();
  for (int item = t; item < NN * 4; item += 256) {
    int n = item >> 2, fg = item & 3;
    float4 r = make_float4(0.f, 0.f, 0.f, 0.f);
    int e1 = rp[n + 1];
    for (int e = rp[n]; e < e1; ++e) {
      int2 p = cs[e];
      float nw = __int_as_float(p.y);
      float4 sv = *(const float4*)(T + p.x * 16 + fg * 4);
      r.x += nw * sv.x; r.y += nw * sv.y; r.z += nw * sv.z; r.w += nw * sv.w;
    }
    int f0 = fb + fg * 4;
    float4 y0 = *(const float4*)(Yg + n * 96 + f0);
    float4 y2 = *(const float4*)(Yg + n * 96 + 64 + f0);
    float4 s2 = *(const float4*)(S + n * 16 + fg * 4);
    float rr[4] = {r.x, r.y, r.z, r.w};
    float y0a[4] = {y0.x, y0.y, y0.z, y0.w};
    float y2a[4] = {y2.x, y2.y, y2.z, y2.w};
    float s2a[4] = {s2.x, s2.y, s2.z, s2.w};
    float* base = H2T + (size_t)g * 32 * NN;
#pragma unroll
    for (int i = 0; i < 4; ++i) {
      float v = fmaxf(y0a[i] - y2a[i] + rr[i] + 2.f * s2a[i] + b4[f0 + i], 0.f);
      base[(size_t)(f0 + i) * NN + n] = v;
    }
  }
}

// ---------------------------------------------------------------------------
// K6/K7: plain GEMM + bias (+relu). A:[M x KD], W:[KD x NC], out:[M x NC].
// ---------------------------------------------------------------------------
template <int KD, int NC, int NCP, int TNT, bool RELU>
__global__ __launch_bounds__(256) void k_gemm_bias(
    const float* __restrict__ A, const float* __restrict__ W,
    const float* __restrict__ bias, float* __restrict__ out, int M) {
  int m0 = blockIdx.x * 64;
  __shared__ float As[64][17];
  __shared__ float Bs[16][NCP];
  int t = threadIdx.x;
  int tx = t & 15, ty = t >> 4;
  float acc[4][TNT];
#pragma unroll
  for (int i = 0; i < 4; ++i)
#pragma unroll
    for (int j = 0; j < TNT; ++j) acc[i][j] = 0.f;

  for (int k0 = 0; k0 < KD; k0 += 16) {
    int klim = KD - k0; if (klim > 16) klim = 16;
    {
      int kk = t & 15, rb = t >> 4;
#pragma unroll
      for (int i = 0; i < 4; ++i) {
        int r = rb + i * 16;
        int row = m0 + r;
        As[r][kk] = (row < M && kk < klim) ? A[(size_t)row * KD + k0 + kk] : 0.f;
      }
    }
    for (int i = t; i < 16 * NCP; i += 256) {
      int kk = i / NCP, c = i - kk * NCP;
      Bs[kk][c] = (kk < klim && c < NC) ? W[(size_t)(k0 + kk) * NC + c] : 0.f;
    }
    __syncthreads();
#pragma unroll
    for (int kk = 0; kk < 16; ++kk) {
      float a[4];
#pragma unroll
      for (int i = 0; i < 4; ++i) a[i] = As[ty * 4 + i][kk];
#pragma unroll
      for (int j = 0; j < TNT; ++j) {
        float b = Bs[kk][tx * TNT + j];
#pragma unroll
        for (int i = 0; i < 4; ++i) acc[i][j] += a[i] * b;
      }
    }
    __syncthreads();
  }
#pragma unroll
  for (int i = 0; i < 4; ++i) {
    int row = m0 + ty * 4 + i;
    if (row < M) {
#pragma unroll
      for (int j = 0; j < TNT; ++j) {
        int c = tx * TNT + j;
        if (c < NC) {
          float v = acc[i][j] + bias[c];
          if (RELU) v = fmaxf(v, 0.f);
          out[(size_t)row * NC + c] = v;
        }
      }
    }
  }
}

// ---------------------------------------------------------------------------
// K8: out[r] = Z2[r][:] . Wc3 + bc3  (r = g*32 + c, matches d_out layout)
// ---------------------------------------------------------------------------
__global__ __launch_bounds__(256) void k_final(
    const float* __restrict__ Z2, const float* __restrict__ Wc3,
    const float* __restrict__ bc3, float* __restrict__ out) {
  __shared__ float Zs[256 * 61];
  __shared__ float w3[60];
  int b = blockIdx.x, t = threadIdx.x;
  const float* src = Z2 + (size_t)b * 256 * 60;
  for (int i = t; i < 256 * 60; i += 256) {
    int row = i / 60, col = i - row * 60;
    Zs[row * 61 + col] = src[i];
  }
  if (t < 60) w3[t] = Wc3[t];
  __syncthreads();
  float acc = bc3[0];
#pragma unroll
  for (int k = 0; k < 60; ++k) acc += Zs[t * 61 + k] * w3[k];
  out[(size_t)b * 256 + t] = acc;
}

// ---------------------------------------------------------------------------
// Workspace layout (bytes):
//   0         csr   int2[128][8192]          8,388,608
//   8388608   rp    int [128][272]             139,264
//   8527872   Y     f32 [128][268][192]     26,345,472  (reused as Y2b [..][96] by K4/K5)
//   34873344  H1    f32 [128][268][64]       8,781,824  (reused as H2T [128][32][268] by K5+)
//   39264256  Z1    f32 [128][32][100]       1,638,400
//   40902656  Z2    f32 [128][32][60]          983,040
// total ~41.9 MB
// ---------------------------------------------------------------------------
extern "C" void kernel_launch(void* const* d_in, const int* in_sizes, int n_in,
                              void* d_out, int out_size, void* d_ws, size_t ws_size,
                              hipStream_t stream) {
  (void)in_sizes; (void)n_in; (void)out_size; (void)ws_size;
  const float* x1  = (const float*)d_in[0];
  const int*   ei1 = (const int*)d_in[1];
  const float* ea1 = (const float*)d_in[2];
  const float* x2  = (const float*)d_in[3];
  const int*   ei2 = (const int*)d_in[4];
  const float* ea2 = (const float*)d_in[5];
  const float* W1  = (const float*)d_in[6];
  const float* b1  = (const float*)d_in[7];
  const float* W4  = (const float*)d_in[8];
  const float* b4  = (const float*)d_in[9];
  const float* Wc1 = (const float*)d_in[10];
  const float* bc1 = (const float*)d_in[11];
  const float* Wc2 = (const float*)d_in[12];
  const float* bc2 = (const float*)d_in[13];
  const float* Wc3 = (const float*)d_in[14];
  const float* bc3 = (const float*)d_in[15];

  char* ws = (char*)d_ws;
  int2*  csr = (int2*)(ws + 0);
  int*   rp  = (int*)(ws + 8388608);
  float* Y   = (float*)(ws + 8527872);
  float* H1  = (float*)(ws + 34873344);
  float* H2T = (float*)(ws + 34873344);
  float* Z1  = (float*)(ws + 39264256);
  float* Z2  = (float*)(ws + 40902656);
  float* out = (float*)d_out;

  k_edge_prep<<<128, 256, 0, stream>>>(ei1, ea1, ei2, ea2, csr, rp);
  // Y = X @ [W1_0|W1_1|W1_2]   (M=268/graph, K=268, N=192)
  k_gemm_cat<268, 192, 64, 12><<<dim3(5, 128), 256, 0, stream>>>(x1, x2, W1, Y);
  // H1 = relu(Y0 - Y2 + L*Y1 + 2*L*L*Y2 + b1)
  k_cheb1<<<dim3(4, 128), 256, 0, stream>>>(Y, csr, rp, b1, H1);
  // Y2b = H1 @ [W4_0|W4_1|W4_2]  (K=64, N=96), written over the Y region
  k_gemm_cat<64, 96, 32, 6><<<dim3(5, 128), 256, 0, stream>>>(
      H1, H1 + (size_t)64 * NN * 64, W4, Y);
  // H2T = relu(cheb2) transposed -> [g][32][268], written over H1 region
  k_cheb2<<<dim3(2, 128), 256, 0, stream>>>(Y, csr, rp, b4, H2T);
  // classifier: stacked rows M = 128*32 = 4096 share weights
  k_gemm_bias<268, 100, 112, 7, true><<<64, 256, 0, stream>>>(H2T, Wc1, bc1, Z1, 4096);
  k_gemm_bias<100, 60, 64, 4, true><<<64, 256, 0, stream>>>(Z1, Wc2, bc2, Z2, 4096);
  k_final<<<16, 256, 0, stream>>>(Z2, Wc3, bc3, out);
}